// Round 1
// baseline (826.722 us; speedup 1.0000x reference)
//
#include <hip/hip_runtime.h>
#include <hip/hip_bf16.h>
#include <math.h>

#define B_ 32
#define C_ 512
#define N_ 1024
#define D_ 64
#define O_ 576   // D + C combined output channels for the fused W1/W2 GEMM

typedef __attribute__((ext_vector_type(4))) float f32x4;
typedef __attribute__((ext_vector_type(8))) __bf16 bf16x8;

#define MFMA16(a, b, c) __builtin_amdgcn_mfma_f32_16x16x32_bf16((a), (b), (c), 0, 0, 0)

// ---------------------------------------------------------------------------
// K1a: cast w1 (rows 0..63) + w2 (rows 64..575) into combined bf16 W [576,512]
// ---------------------------------------------------------------------------
__global__ void k_cast_weights(const float* __restrict__ w1,
                               const float* __restrict__ w2,
                               __hip_bfloat16* __restrict__ Wbf) {
    int idx = blockIdx.x * 256 + threadIdx.x;
    if (idx >= O_ * C_) return;
    int m = idx >> 9;          // /512
    int k = idx & (C_ - 1);
    float val = (m < D_) ? w1[m * C_ + k] : w2[(m - D_) * C_ + k];
    Wbf[idx] = __float2bfloat16(val);
}

// ---------------------------------------------------------------------------
// K1b: transpose-cast x [B,C,N] fp32 -> xT [B,N,C] bf16 (LDS 32x32 tiles)
// ---------------------------------------------------------------------------
__global__ void k_transpose_cast(const float* __restrict__ x,
                                 __hip_bfloat16* __restrict__ xT) {
    __shared__ float tile[32][33];
    int b = blockIdx.z;
    int n0 = blockIdx.x * 32;
    int c0 = blockIdx.y * 32;
    int tx = threadIdx.x;   // 0..31
    int ty = threadIdx.y;   // 0..7
    const float* xb = x + (size_t)b * (C_ * N_);
#pragma unroll
    for (int i = 0; i < 4; i++) {
        int c = ty + i * 8;
        tile[c][tx] = xb[(size_t)(c0 + c) * N_ + n0 + tx];   // coalesced in n
    }
    __syncthreads();
    __hip_bfloat16* xTb = xT + (size_t)b * (N_ * C_);
#pragma unroll
    for (int i = 0; i < 4; i++) {
        int n = ty + i * 8;
        xTb[(size_t)(n0 + n) * C_ + c0 + tx] = __float2bfloat16(tile[tx][n]); // coalesced in c
    }
}

// ---------------------------------------------------------------------------
// K2: per-batch GEMM  W[576,512] x xT[b]^T -> qkT [B,N,D] bf16 (transposed
// store) and v [B,C,N] bf16.  Tile: block 64 rows x 64 cols, wave = 16 rows.
// A frag: W[m=lane&15][k=quad*8+j] (contiguous).  B frag: xT[n][k] contiguous.
// ---------------------------------------------------------------------------
__global__ __launch_bounds__(256) void k_gemm_qkv(
        const __hip_bfloat16* __restrict__ Wbf,
        const __hip_bfloat16* __restrict__ xT,
        const float* __restrict__ b1, const float* __restrict__ b2,
        __hip_bfloat16* __restrict__ qkT, __hip_bfloat16* __restrict__ v) {
    int b    = blockIdx.z;
    int wave = threadIdx.x >> 6;
    int lane = threadIdx.x & 63;
    int lr   = lane & 15;
    int quad = lane >> 4;
    int m_base = blockIdx.y * 64 + wave * 16;
    int n_base = blockIdx.x * 64;
    const __hip_bfloat16* xTb = xT + (size_t)b * (N_ * C_);

    f32x4 acc[4] = {};
    for (int kk = 0; kk < C_; kk += 32) {
        bf16x8 a = *(const bf16x8*)(Wbf + (size_t)(m_base + lr) * C_ + kk + quad * 8);
#pragma unroll
        for (int ct = 0; ct < 4; ct++) {
            bf16x8 bb = *(const bf16x8*)(xTb + (size_t)(n_base + ct * 16 + lr) * C_ + kk + quad * 8);
            acc[ct] = MFMA16(a, bb, acc[ct]);
        }
    }

    int m0 = m_base + quad * 4;           // 4 consecutive output rows (reg idx)
    if (m_base < D_) {
        // q/k channels -> store transposed qkT[b][n][d], 4 contiguous d per lane
        float bias[4];
#pragma unroll
        for (int r = 0; r < 4; r++) bias[r] = b1[m0 + r];
#pragma unroll
        for (int ct = 0; ct < 4; ct++) {
            int n = n_base + ct * 16 + lr;
            alignas(8) __hip_bfloat16 tmp[4];
#pragma unroll
            for (int r = 0; r < 4; r++)
                tmp[r] = __float2bfloat16(acc[ct][r] + bias[r]);
            *reinterpret_cast<short4*>(qkT + ((size_t)b * N_ + n) * D_ + m0) =
                *reinterpret_cast<short4*>(tmp);
        }
    } else {
        // v channels -> store v[b][c][n] (n-major rows, scalar bf16 stores)
#pragma unroll
        for (int ct = 0; ct < 4; ct++) {
            int n = n_base + ct * 16 + lr;
#pragma unroll
            for (int r = 0; r < 4; r++) {
                int c = m0 - D_ + r;
                v[((size_t)b * C_ + c) * N_ + n] = __float2bfloat16(acc[ct][r] + b2[c]);
            }
        }
    }
}

// ---------------------------------------------------------------------------
// K3: row stats (softmax max & 1/sumexp) over logits S = qk^T qk (no scale!)
// grid (N/64, B), 4 waves x 16 q-rows each. Online per-lane, then 16-lane
// shuffle reduce within each quad group.
// ---------------------------------------------------------------------------
__global__ __launch_bounds__(256) void k_row_stats(
        const __hip_bfloat16* __restrict__ qkT,
        float* __restrict__ rowmax, float* __restrict__ rowinv) {
    int b    = blockIdx.y;
    int wave = threadIdx.x >> 6;
    int lane = threadIdx.x & 63;
    int lr   = lane & 15;
    int quad = lane >> 4;
    int q0 = blockIdx.x * 64 + wave * 16;
    const __hip_bfloat16* qb = qkT + (size_t)b * (N_ * D_);

    bf16x8 a0 = *(const bf16x8*)(qb + (size_t)(q0 + lr) * D_ + quad * 8);
    bf16x8 a1 = *(const bf16x8*)(qb + (size_t)(q0 + lr) * D_ + 32 + quad * 8);

    float mr[4], sr[4];
#pragma unroll
    for (int r = 0; r < 4; r++) { mr[r] = -INFINITY; sr[r] = 0.0f; }

    for (int m0 = 0; m0 < N_; m0 += 16) {
        bf16x8 k0 = *(const bf16x8*)(qb + (size_t)(m0 + lr) * D_ + quad * 8);
        bf16x8 k1 = *(const bf16x8*)(qb + (size_t)(m0 + lr) * D_ + 32 + quad * 8);
        f32x4 s = {};
        s = MFMA16(a0, k0, s);
        s = MFMA16(a1, k1, s);
#pragma unroll
        for (int r = 0; r < 4; r++) {
            float sv = s[r];
            float mn = fmaxf(mr[r], sv);
            sr[r] = sr[r] * __expf(mr[r] - mn) + __expf(sv - mn);
            mr[r] = mn;
        }
    }
    // combine across the 16 lanes (cols) of each quad group
#pragma unroll
    for (int off = 1; off < 16; off <<= 1) {
#pragma unroll
        for (int r = 0; r < 4; r++) {
            float om = __shfl_xor(mr[r], off);
            float os = __shfl_xor(sr[r], off);
            float mn = fmaxf(mr[r], om);
            sr[r] = sr[r] * __expf(mr[r] - mn) + os * __expf(om - mn);
            mr[r] = mn;
        }
    }
    if (lr == 0) {
#pragma unroll
        for (int r = 0; r < 4; r++) {
            int n = q0 + quad * 4 + r;
            rowmax[b * N_ + n] = mr[r];
            rowinv[b * N_ + n] = 1.0f / sr[r];
        }
    }
}

// ---------------------------------------------------------------------------
// K4: fused  S -> P=exp(S-max)*inv -> (LDS A-layout) -> O += P*V^T, + residual
// grid (N/64, B), 4 waves x 16 q-rows. Per wave acc = 16 rows x 512 cols
// (32 tiles, 128 acc VGPRs/lane). m-step = 32 (one PV K per step).
// Output quirk: out_flat[b][n*512+c] = x_flat[b][n*512+c] + O[n][c].
// ---------------------------------------------------------------------------
__global__ __launch_bounds__(256) void k_attn_pv(
        const __hip_bfloat16* __restrict__ qkT,
        const __hip_bfloat16* __restrict__ v,
        const float* __restrict__ rowmax, const float* __restrict__ rowinv,
        const float* __restrict__ x, float* __restrict__ out) {
    __shared__ __hip_bfloat16 plds[4][16][32];   // per-wave P tile, A-layout source
    int b    = blockIdx.y;
    int wave = threadIdx.x >> 6;
    int lane = threadIdx.x & 63;
    int lr   = lane & 15;
    int quad = lane >> 4;
    int q0 = blockIdx.x * 64 + wave * 16;
    const __hip_bfloat16* qb = qkT + (size_t)b * (N_ * D_);
    const __hip_bfloat16* vb = v + (size_t)b * (C_ * N_);

    bf16x8 a0 = *(const bf16x8*)(qb + (size_t)(q0 + lr) * D_ + quad * 8);
    bf16x8 a1 = *(const bf16x8*)(qb + (size_t)(q0 + lr) * D_ + 32 + quad * 8);

    float rm[4], ri[4];
#pragma unroll
    for (int r = 0; r < 4; r++) {
        int n = q0 + quad * 4 + r;
        rm[r] = rowmax[b * N_ + n];
        ri[r] = rowinv[b * N_ + n];
    }

    f32x4 acc[32] = {};

    for (int m0 = 0; m0 < N_; m0 += 32) {
#pragma unroll
        for (int t = 0; t < 2; t++) {
            int mm = m0 + t * 16;
            bf16x8 k0 = *(const bf16x8*)(qb + (size_t)(mm + lr) * D_ + quad * 8);
            bf16x8 k1 = *(const bf16x8*)(qb + (size_t)(mm + lr) * D_ + 32 + quad * 8);
            f32x4 s = {};
            s = MFMA16(a0, k0, s);
            s = MFMA16(a1, k1, s);
#pragma unroll
            for (int r = 0; r < 4; r++) {
                float p = __expf(s[r] - rm[r]) * ri[r];   // final normalized prob
                plds[wave][quad * 4 + r][t * 16 + lr] = __float2bfloat16(p);
            }
        }
        // same-wave LDS RAW; DS pipe is in-order per wave, compiler adds lgkmcnt
        bf16x8 pa = *(const bf16x8*)(&plds[wave][lr][quad * 8]);
#pragma unroll
        for (int ct = 0; ct < 32; ct++) {
            bf16x8 bv = *(const bf16x8*)(vb + (size_t)(ct * 16 + lr) * N_ + m0 + quad * 8);
            acc[ct] = MFMA16(pa, bv, acc[ct]);
        }
    }

    // epilogue: flat residual add (reshape quirk => same flat index)
    const float* xb = x + (size_t)b * (N_ * C_);
    float* ob = out + (size_t)b * (N_ * C_);
#pragma unroll
    for (int ct = 0; ct < 32; ct++) {
#pragma unroll
        for (int r = 0; r < 4; r++) {
            int n = q0 + quad * 4 + r;
            int c = ct * 16 + lr;
            size_t idx = (size_t)n * C_ + c;
            ob[idx] = xb[idx] + acc[ct][r];
        }
    }
}

// ---------------------------------------------------------------------------
extern "C" void kernel_launch(void* const* d_in, const int* in_sizes, int n_in,
                              void* d_out, int out_size, void* d_ws, size_t ws_size,
                              hipStream_t stream) {
    const float* x  = (const float*)d_in[0];
    const float* w1 = (const float*)d_in[1];
    const float* b1 = (const float*)d_in[2];
    const float* w2 = (const float*)d_in[3];
    const float* b2 = (const float*)d_in[4];
    float* out = (float*)d_out;

    char* ws = (char*)d_ws;
    size_t off = 0;
    __hip_bfloat16* Wbf = (__hip_bfloat16*)(ws + off); off += (size_t)O_ * C_ * 2;        // 589,824
    __hip_bfloat16* xT  = (__hip_bfloat16*)(ws + off); off += (size_t)B_ * N_ * C_ * 2;   // 33,554,432
    __hip_bfloat16* qkT = (__hip_bfloat16*)(ws + off); off += (size_t)B_ * N_ * D_ * 2;   // 4,194,304
    __hip_bfloat16* v   = (__hip_bfloat16*)(ws + off); off += (size_t)B_ * C_ * N_ * 2;   // 33,554,432
    float* rowmax = (float*)(ws + off); off += (size_t)B_ * N_ * 4;
    float* rowinv = (float*)(ws + off); off += (size_t)B_ * N_ * 4;

    hipLaunchKernelGGL(k_cast_weights, dim3((O_ * C_ + 255) / 256), dim3(256), 0, stream,
                       w1, w2, Wbf);
    hipLaunchKernelGGL(k_transpose_cast, dim3(N_ / 32, C_ / 32, B_), dim3(32, 8), 0, stream,
                       x, xT);
    hipLaunchKernelGGL(k_gemm_qkv, dim3(N_ / 64, O_ / 64, B_), dim3(256), 0, stream,
                       Wbf, xT, b1, b2, qkT, v);
    hipLaunchKernelGGL(k_row_stats, dim3(N_ / 64, B_), dim3(256), 0, stream,
                       qkT, rowmax, rowinv);
    hipLaunchKernelGGL(k_attn_pv, dim3(N_ / 64, B_), dim3(256), 0, stream,
                       qkT, v, rowmax, rowinv, x, out);
}

// Round 2
// 298.608 us; speedup vs baseline: 2.7686x; 2.7686x over previous
//
#include <hip/hip_runtime.h>
#include <hip/hip_bf16.h>
#include <math.h>

#define B_ 32
#define C_ 512
#define N_ 1024
#define D_ 64
#define OPAD 640   // D + C = 576 output channels, padded to 640 for 128-row tiles

typedef __attribute__((ext_vector_type(4))) float f32x4;
typedef __attribute__((ext_vector_type(8))) __bf16 bf16x8;

#define MFMA16(a, b, c) __builtin_amdgcn_mfma_f32_16x16x32_bf16((a), (b), (c), 0, 0, 0)

__device__ inline void load_lds16(const void* g, void* l) {
    __builtin_amdgcn_global_load_lds(
        (const __attribute__((address_space(1))) void*)g,
        (__attribute__((address_space(3))) void*)l, 16, 0, 0);
}

// ---------------------------------------------------------------------------
// K1a: cast w1 (rows 0..63) + w2 (rows 64..575) into bf16 W [640,512], rows
// 576..639 zeroed (so 128-row tile staging never reads poison as signal).
// ---------------------------------------------------------------------------
__global__ void k_cast_weights(const float* __restrict__ w1,
                               const float* __restrict__ w2,
                               __hip_bfloat16* __restrict__ Wbf) {
    int idx = blockIdx.x * 256 + threadIdx.x;
    if (idx >= OPAD * C_) return;
    int m = idx >> 9;
    int k = idx & (C_ - 1);
    float val = (m < D_) ? w1[m * C_ + k]
              : (m < D_ + C_) ? w2[(m - D_) * C_ + k] : 0.0f;
    Wbf[idx] = __float2bfloat16(val);
}

// ---------------------------------------------------------------------------
// K1b: transpose-cast x [B,C,N] fp32 -> xT [B,N,C] bf16 (LDS 32x32 tiles)
// ---------------------------------------------------------------------------
__global__ void k_transpose_cast(const float* __restrict__ x,
                                 __hip_bfloat16* __restrict__ xT) {
    __shared__ float tile[32][33];
    int b = blockIdx.z;
    int n0 = blockIdx.x * 32;
    int c0 = blockIdx.y * 32;
    int tx = threadIdx.x;
    int ty = threadIdx.y;
    const float* xb = x + (size_t)b * (C_ * N_);
#pragma unroll
    for (int i = 0; i < 4; i++) {
        int c = ty + i * 8;
        tile[c][tx] = xb[(size_t)(c0 + c) * N_ + n0 + tx];
    }
    __syncthreads();
    __hip_bfloat16* xTb = xT + (size_t)b * (N_ * C_);
#pragma unroll
    for (int i = 0; i < 4; i++) {
        int n = ty + i * 8;
        xTb[(size_t)(n0 + n) * C_ + c0 + tx] = __float2bfloat16(tile[tx][n]);
    }
}

// ---------------------------------------------------------------------------
// K2: LDS-staged GEMM  W[640,512] x xT[b][n][c] -> qkT [B,N,D] + v [B,C,N].
// m97 structure: 128x128 tile, BK=32, global_load_lds width 16, 2 barriers.
// grid (N/128, OPAD/128, B), block 256 (4 waves in 2x2).
// ---------------------------------------------------------------------------
__global__ __launch_bounds__(256) void k_gemm_qkv(
        const __hip_bfloat16* __restrict__ Wbf,
        const __hip_bfloat16* __restrict__ xT,
        const float* __restrict__ b1, const float* __restrict__ b2,
        __hip_bfloat16* __restrict__ qkT, __hip_bfloat16* __restrict__ v) {
    __shared__ __hip_bfloat16 As[128 * 32];   // [row][k], unpadded (load_lds rule)
    __shared__ __hip_bfloat16 Bs[128 * 32];
    int b = blockIdx.z;
    int t = threadIdx.x;
    int wave = t >> 6, lane = t & 63, lr = lane & 15, quad = lane >> 4;
    int wm = wave >> 1, wn = wave & 1;
    int m_blk = blockIdx.y * 128;
    int n_blk = blockIdx.x * 128;
    const __hip_bfloat16* xTb = xT + (size_t)b * (N_ * C_);

    f32x4 acc[4][4] = {};
    for (int kk = 0; kk < C_; kk += 32) {
#pragma unroll
        for (int j = 0; j < 2; j++) {
            int row = j * 64 + (t >> 2);
            int col = kk + (t & 3) * 8;
            load_lds16(Wbf + (size_t)(m_blk + row) * C_ + col, &As[j * 2048 + t * 8]);
            load_lds16(xTb + (size_t)(n_blk + row) * C_ + col, &Bs[j * 2048 + t * 8]);
        }
        __syncthreads();
        bf16x8 af[4], bf[4];
#pragma unroll
        for (int i = 0; i < 4; i++) {
            af[i] = *(const bf16x8*)&As[(wm * 64 + i * 16 + lr) * 32 + quad * 8];
            bf[i] = *(const bf16x8*)&Bs[(wn * 64 + i * 16 + lr) * 32 + quad * 8];
        }
#pragma unroll
        for (int mt = 0; mt < 4; mt++)
#pragma unroll
            for (int nt = 0; nt < 4; nt++)
                acc[mt][nt] = MFMA16(af[mt], bf[nt], acc[mt][nt]);
        __syncthreads();
    }

#pragma unroll
    for (int mt = 0; mt < 4; mt++) {
        int m_frag = m_blk + wm * 64 + mt * 16;      // uniform per frag (16-aligned)
        if (m_frag >= D_ + C_) continue;
        int m0 = m_frag + quad * 4;
#pragma unroll
        for (int nt = 0; nt < 4; nt++) {
            int n = n_blk + wn * 64 + nt * 16 + lr;
            if (m_frag < D_) {
                alignas(8) __hip_bfloat16 tmp[4];
#pragma unroll
                for (int r = 0; r < 4; r++)
                    tmp[r] = __float2bfloat16(acc[mt][nt][r] + b1[m0 + r]);
                *reinterpret_cast<short4*>(qkT + ((size_t)b * N_ + n) * D_ + m0) =
                    *reinterpret_cast<short4*>(tmp);
            } else {
#pragma unroll
                for (int r = 0; r < 4; r++) {
                    int c = m0 - D_ + r;
                    v[((size_t)b * C_ + c) * N_ + n] =
                        __float2bfloat16(acc[mt][nt][r] + b2[c]);
                }
            }
        }
    }
}

// ---------------------------------------------------------------------------
// K3: row stats (softmax max & 1/sumexp) over S = qk^T qk.
// ---------------------------------------------------------------------------
__global__ __launch_bounds__(256) void k_row_stats(
        const __hip_bfloat16* __restrict__ qkT,
        float* __restrict__ rowmax, float* __restrict__ rowinv) {
    int b = blockIdx.y;
    int wave = threadIdx.x >> 6, lane = threadIdx.x & 63;
    int lr = lane & 15, quad = lane >> 4;
    int q0 = blockIdx.x * 64 + wave * 16;
    const __hip_bfloat16* qb = qkT + (size_t)b * (N_ * D_);

    bf16x8 a0 = *(const bf16x8*)(qb + (size_t)(q0 + lr) * D_ + quad * 8);
    bf16x8 a1 = *(const bf16x8*)(qb + (size_t)(q0 + lr) * D_ + 32 + quad * 8);

    float mr[4], sr[4];
#pragma unroll
    for (int r = 0; r < 4; r++) { mr[r] = -INFINITY; sr[r] = 0.0f; }

    for (int m0 = 0; m0 < N_; m0 += 16) {
        bf16x8 k0 = *(const bf16x8*)(qb + (size_t)(m0 + lr) * D_ + quad * 8);
        bf16x8 k1 = *(const bf16x8*)(qb + (size_t)(m0 + lr) * D_ + 32 + quad * 8);
        f32x4 s = {};
        s = MFMA16(a0, k0, s);
        s = MFMA16(a1, k1, s);
#pragma unroll
        for (int r = 0; r < 4; r++) {
            float sv = s[r];
            float mn = fmaxf(mr[r], sv);
            sr[r] = sr[r] * __expf(mr[r] - mn) + __expf(sv - mn);
            mr[r] = mn;
        }
    }
#pragma unroll
    for (int off = 1; off < 16; off <<= 1) {
#pragma unroll
        for (int r = 0; r < 4; r++) {
            float om = __shfl_xor(mr[r], off);
            float os = __shfl_xor(sr[r], off);
            float mn = fmaxf(mr[r], om);
            sr[r] = sr[r] * __expf(mr[r] - mn) + os * __expf(om - mn);
            mr[r] = mn;
        }
    }
    if (lr == 0) {
#pragma unroll
        for (int r = 0; r < 4; r++) {
            int n = q0 + quad * 4 + r;
            rowmax[b * N_ + n] = mr[r];
            rowinv[b * N_ + n] = 1.0f / sr[r];
        }
    }
}

// ---------------------------------------------------------------------------
// K4a: materialize P[b][n][m] = exp(S - rowmax)*rowinv  (bf16, 64 MB)
// grid (N/64, B), 4 waves x 16 q-rows. Stores: lane -> m contiguous.
// ---------------------------------------------------------------------------
__global__ __launch_bounds__(256) void k_build_p(
        const __hip_bfloat16* __restrict__ qkT,
        const float* __restrict__ rowmax, const float* __restrict__ rowinv,
        __hip_bfloat16* __restrict__ P) {
    int b = blockIdx.y;
    int wave = threadIdx.x >> 6, lane = threadIdx.x & 63;
    int lr = lane & 15, quad = lane >> 4;
    int q0 = blockIdx.x * 64 + wave * 16;
    const __hip_bfloat16* qb = qkT + (size_t)b * (N_ * D_);
    __hip_bfloat16* Pb = P + ((size_t)b << 20);   // N_*N_ = 1<<20

    bf16x8 a0 = *(const bf16x8*)(qb + (size_t)(q0 + lr) * D_ + quad * 8);
    bf16x8 a1 = *(const bf16x8*)(qb + (size_t)(q0 + lr) * D_ + 32 + quad * 8);

    float rm[4], ri[4];
#pragma unroll
    for (int r = 0; r < 4; r++) {
        int n = q0 + quad * 4 + r;
        rm[r] = rowmax[b * N_ + n];
        ri[r] = rowinv[b * N_ + n];
    }

    for (int m0 = 0; m0 < N_; m0 += 16) {
        bf16x8 k0 = *(const bf16x8*)(qb + (size_t)(m0 + lr) * D_ + quad * 8);
        bf16x8 k1 = *(const bf16x8*)(qb + (size_t)(m0 + lr) * D_ + 32 + quad * 8);
        f32x4 s = {};
        s = MFMA16(a0, k0, s);
        s = MFMA16(a1, k1, s);
#pragma unroll
        for (int r = 0; r < 4; r++) {
            float p = __expf(s[r] - rm[r]) * ri[r];
            Pb[(size_t)(q0 + quad * 4 + r) * N_ + m0 + lr] = __float2bfloat16(p);
        }
    }
}

// ---------------------------------------------------------------------------
// K4b: O[n][c] = sum_m P[n][m] * v[c][m], + flat residual.  m97 structure.
// grid (C/128, N/128, B), block 256.  K = N_ = 1024.
// ---------------------------------------------------------------------------
__global__ __launch_bounds__(256) void k_pv_gemm(
        const __hip_bfloat16* __restrict__ P,
        const __hip_bfloat16* __restrict__ v,
        const float* __restrict__ x, float* __restrict__ out) {
    __shared__ __hip_bfloat16 As[128 * 32];   // P rows  [n][m-chunk]
    __shared__ __hip_bfloat16 Bs[128 * 32];   // v rows  [c][m-chunk]
    int b = blockIdx.z;
    int t = threadIdx.x;
    int wave = t >> 6, lane = t & 63, lr = lane & 15, quad = lane >> 4;
    int wm = wave >> 1, wn = wave & 1;
    int n_blk = blockIdx.y * 128;   // q rows
    int c_blk = blockIdx.x * 128;   // channels
    const __hip_bfloat16* Pb = P + ((size_t)b << 20);
    const __hip_bfloat16* vb = v + (size_t)b * (C_ * N_);

    f32x4 acc[4][4] = {};
    for (int kk = 0; kk < N_; kk += 32) {
#pragma unroll
        for (int j = 0; j < 2; j++) {
            int row = j * 64 + (t >> 2);
            int col = kk + (t & 3) * 8;
            load_lds16(Pb + (size_t)(n_blk + row) * N_ + col, &As[j * 2048 + t * 8]);
            load_lds16(vb + (size_t)(c_blk + row) * N_ + col, &Bs[j * 2048 + t * 8]);
        }
        __syncthreads();
        bf16x8 af[4], bf[4];
#pragma unroll
        for (int i = 0; i < 4; i++) {
            af[i] = *(const bf16x8*)&As[(wm * 64 + i * 16 + lr) * 32 + quad * 8];
            bf[i] = *(const bf16x8*)&Bs[(wn * 64 + i * 16 + lr) * 32 + quad * 8];
        }
#pragma unroll
        for (int mt = 0; mt < 4; mt++)
#pragma unroll
            for (int nt = 0; nt < 4; nt++)
                acc[mt][nt] = MFMA16(af[mt], bf[nt], acc[mt][nt]);
        __syncthreads();
    }

    // epilogue: out_flat[b][n*512+c] = x_flat + O[n][c]   (reshape quirk)
    const float* xb = x + (size_t)b * (N_ * C_);
    float* ob = out + (size_t)b * (N_ * C_);
#pragma unroll
    for (int mt = 0; mt < 4; mt++) {
#pragma unroll
        for (int nt = 0; nt < 4; nt++) {
#pragma unroll
            for (int r = 0; r < 4; r++) {
                int n = n_blk + wm * 64 + mt * 16 + quad * 4 + r;
                int c = c_blk + wn * 64 + nt * 16 + lr;
                size_t idx = (size_t)n * C_ + c;
                ob[idx] = xb[idx] + acc[mt][nt][r];
            }
        }
    }
}

// ---------------------------------------------------------------------------
extern "C" void kernel_launch(void* const* d_in, const int* in_sizes, int n_in,
                              void* d_out, int out_size, void* d_ws, size_t ws_size,
                              hipStream_t stream) {
    const float* x  = (const float*)d_in[0];
    const float* w1 = (const float*)d_in[1];
    const float* b1 = (const float*)d_in[2];
    const float* w2 = (const float*)d_in[3];
    const float* b2 = (const float*)d_in[4];
    float* out = (float*)d_out;

    char* ws = (char*)d_ws;
    size_t off = 0;
    __hip_bfloat16* Wbf = (__hip_bfloat16*)(ws + off); off += (size_t)OPAD * C_ * 2;      // 0.66 MB
    __hip_bfloat16* xT  = (__hip_bfloat16*)(ws + off); off += (size_t)B_ * N_ * C_ * 2;   // 32 MB
    __hip_bfloat16* qkT = (__hip_bfloat16*)(ws + off); off += (size_t)B_ * N_ * D_ * 2;   // 4 MB
    __hip_bfloat16* v   = (__hip_bfloat16*)(ws + off); off += (size_t)B_ * C_ * N_ * 2;   // 32 MB
    float* rowmax = (float*)(ws + off); off += (size_t)B_ * N_ * 4;
    float* rowinv = (float*)(ws + off); off += (size_t)B_ * N_ * 4;
    __hip_bfloat16* P = (__hip_bfloat16*)(ws + off); off += (size_t)B_ * N_ * N_ * 2;     // 64 MB

    hipLaunchKernelGGL(k_cast_weights, dim3((OPAD * C_ + 255) / 256), dim3(256), 0, stream,
                       w1, w2, Wbf);
    hipLaunchKernelGGL(k_transpose_cast, dim3(N_ / 32, C_ / 32, B_), dim3(32, 8), 0, stream,
                       x, xT);
    hipLaunchKernelGGL(k_gemm_qkv, dim3(N_ / 128, OPAD / 128, B_), dim3(256), 0, stream,
                       Wbf, xT, b1, b2, qkT, v);
    hipLaunchKernelGGL(k_row_stats, dim3(N_ / 64, B_), dim3(256), 0, stream,
                       qkT, rowmax, rowinv);
    hipLaunchKernelGGL(k_build_p, dim3(N_ / 64, B_), dim3(256), 0, stream,
                       qkT, rowmax, rowinv, P);
    hipLaunchKernelGGL(k_pv_gemm, dim3(C_ / 128, N_ / 128, B_), dim3(256), 0, stream,
                       P, v, x, out);
}

// Round 3
// 291.027 us; speedup vs baseline: 2.8407x; 1.0261x over previous
//
#include <hip/hip_runtime.h>
#include <hip/hip_bf16.h>
#include <math.h>

#define B_ 32
#define C_ 512
#define N_ 1024
#define D_ 64
#define OPAD 640   // D + C = 576 output channels, padded to 640 for 128-row tiles

typedef __attribute__((ext_vector_type(4))) float f32x4;
typedef __attribute__((ext_vector_type(8))) __bf16 bf16x8;

#define MFMA16(a, b, c) __builtin_amdgcn_mfma_f32_16x16x32_bf16((a), (b), (c), 0, 0, 0)

__device__ inline void load_lds16(const void* g, void* l) {
    __builtin_amdgcn_global_load_lds(
        (const __attribute__((address_space(1))) void*)g,
        (__attribute__((address_space(3))) void*)l, 16, 0, 0);
}

// ---------------------------------------------------------------------------
// K1a: cast w1 (rows 0..63) + w2 (rows 64..575) into bf16 W [640,512]
// ---------------------------------------------------------------------------
__global__ void k_cast_weights(const float* __restrict__ w1,
                               const float* __restrict__ w2,
                               __hip_bfloat16* __restrict__ Wbf) {
    int idx = blockIdx.x * 256 + threadIdx.x;
    if (idx >= OPAD * C_) return;
    int m = idx >> 9;
    int k = idx & (C_ - 1);
    float val = (m < D_) ? w1[m * C_ + k]
              : (m < D_ + C_) ? w2[(m - D_) * C_ + k] : 0.0f;
    Wbf[idx] = __float2bfloat16(val);
}

// ---------------------------------------------------------------------------
// K1b: transpose-cast x [B,C,N] fp32 -> xT [B,N,C] bf16 (LDS 32x32 tiles)
// ---------------------------------------------------------------------------
__global__ void k_transpose_cast(const float* __restrict__ x,
                                 __hip_bfloat16* __restrict__ xT) {
    __shared__ float tile[32][33];
    int b = blockIdx.z;
    int n0 = blockIdx.x * 32;
    int c0 = blockIdx.y * 32;
    int tx = threadIdx.x;
    int ty = threadIdx.y;
    const float* xb = x + (size_t)b * (C_ * N_);
#pragma unroll
    for (int i = 0; i < 4; i++) {
        int c = ty + i * 8;
        tile[c][tx] = xb[(size_t)(c0 + c) * N_ + n0 + tx];
    }
    __syncthreads();
    __hip_bfloat16* xTb = xT + (size_t)b * (N_ * C_);
#pragma unroll
    for (int i = 0; i < 4; i++) {
        int n = ty + i * 8;
        xTb[(size_t)(n0 + n) * C_ + c0 + tx] = __float2bfloat16(tile[tx][n]);
    }
}

// ---------------------------------------------------------------------------
// K2: LDS-staged GEMM  W[640,512] x xT -> qkT [B,N,D] + v [B,C,N].
// m97 structure. v-epilogue staged through LDS for 16B coalesced stores.
// ---------------------------------------------------------------------------
__global__ __launch_bounds__(256) void k_gemm_qkv(
        const __hip_bfloat16* __restrict__ Wbf,
        const __hip_bfloat16* __restrict__ xT,
        const float* __restrict__ b1, const float* __restrict__ b2,
        __hip_bfloat16* __restrict__ qkT, __hip_bfloat16* __restrict__ v) {
    __shared__ __hip_bfloat16 As[128 * 32];
    __shared__ __hip_bfloat16 Bs[128 * 32];
    __shared__ __hip_bfloat16 epi[4][16][72];   // 64 cols + 8 pad (16B-aligned rows)
    int b = blockIdx.z;
    int t = threadIdx.x;
    int wave = t >> 6, lane = t & 63, lr = lane & 15, quad = lane >> 4;
    int wm = wave >> 1, wn = wave & 1;
    int m_blk = blockIdx.y * 128;
    int n_blk = blockIdx.x * 128;
    const __hip_bfloat16* xTb = xT + (size_t)b * (N_ * C_);

    f32x4 acc[4][4] = {};
    for (int kk = 0; kk < C_; kk += 32) {
#pragma unroll
        for (int j = 0; j < 2; j++) {
            int row = j * 64 + (t >> 2);
            int col = kk + (t & 3) * 8;
            load_lds16(Wbf + (size_t)(m_blk + row) * C_ + col, &As[j * 2048 + t * 8]);
            load_lds16(xTb + (size_t)(n_blk + row) * C_ + col, &Bs[j * 2048 + t * 8]);
        }
        __syncthreads();
        bf16x8 af[4], bfr[4];
#pragma unroll
        for (int i = 0; i < 4; i++) {
            af[i] = *(const bf16x8*)&As[(wm * 64 + i * 16 + lr) * 32 + quad * 8];
            bfr[i] = *(const bf16x8*)&Bs[(wn * 64 + i * 16 + lr) * 32 + quad * 8];
        }
#pragma unroll
        for (int mt = 0; mt < 4; mt++)
#pragma unroll
            for (int nt = 0; nt < 4; nt++)
                acc[mt][nt] = MFMA16(af[mt], bfr[nt], acc[mt][nt]);
        __syncthreads();
    }

#pragma unroll
    for (int mt = 0; mt < 4; mt++) {
        int m_frag = m_blk + wm * 64 + mt * 16;
        if (m_frag >= D_ + C_) continue;
        int m0 = m_frag + quad * 4;
        if (m_frag < D_) {
            // q/k rows -> qkT[b][n][d] (4 MB total; 8B stores acceptable)
#pragma unroll
            for (int nt = 0; nt < 4; nt++) {
                int n = n_blk + wn * 64 + nt * 16 + lr;
                alignas(8) __hip_bfloat16 tmp[4];
#pragma unroll
                for (int r = 0; r < 4; r++)
                    tmp[r] = __float2bfloat16(acc[mt][nt][r] + b1[m0 + r]);
                *reinterpret_cast<short4*>(qkT + ((size_t)b * N_ + n) * D_ + m0) =
                    *reinterpret_cast<short4*>(tmp);
            }
        } else {
            // v rows: stage 16x64 subtile in per-wave LDS, flush 16B stores
#pragma unroll
            for (int nt = 0; nt < 4; nt++) {
#pragma unroll
                for (int r = 0; r < 4; r++) {
                    int c = m0 - D_ + r;
                    epi[wave][quad * 4 + r][nt * 16 + lr] =
                        __float2bfloat16(acc[mt][nt][r] + b2[c]);
                }
            }
            int cbase = m_frag - D_;
            int row = lane >> 2;
#pragma unroll
            for (int it = 0; it < 2; it++) {
                int col = it * 32 + (lane & 3) * 8;
                bf16x8 frag = *(const bf16x8*)&epi[wave][row][col];
                *(bf16x8*)(v + (size_t)(b * C_ + cbase + row) * N_
                             + n_blk + wn * 64 + col) = frag;
            }
        }
    }
}

// ---------------------------------------------------------------------------
// K3: fused softmax. Pass 1: online rowmax/rowsum of S = qk^T qk (MFMA +
// 16-lane butterfly). Pass 2: recompute S, P = exp(S-max)*inv, round-trip
// per-wave LDS tile (16x128), flush 16B coalesced stores to P[b][n][m].
// grid (N/64, B), 4 waves x 16 q-rows.
// ---------------------------------------------------------------------------
__global__ __launch_bounds__(256) void k_softmax_p(
        const __hip_bfloat16* __restrict__ qkT,
        __hip_bfloat16* __restrict__ P) {
    __shared__ __hip_bfloat16 pbuf[4][16][136];   // 128 cols + 8 pad (16B rows)
    int b = blockIdx.y;
    int wave = threadIdx.x >> 6, lane = threadIdx.x & 63;
    int lr = lane & 15, quad = lane >> 4;
    int q0 = blockIdx.x * 64 + wave * 16;
    const __hip_bfloat16* qb = qkT + (size_t)b * (N_ * D_);
    __hip_bfloat16* Pb = P + ((size_t)b << 20);

    bf16x8 a0 = *(const bf16x8*)(qb + (size_t)(q0 + lr) * D_ + quad * 8);
    bf16x8 a1 = *(const bf16x8*)(qb + (size_t)(q0 + lr) * D_ + 32 + quad * 8);

    float mr[4], sr[4];
#pragma unroll
    for (int r = 0; r < 4; r++) { mr[r] = -INFINITY; sr[r] = 0.0f; }

    // ---- pass 1: stats ----
    for (int m0 = 0; m0 < N_; m0 += 16) {
        bf16x8 k0 = *(const bf16x8*)(qb + (size_t)(m0 + lr) * D_ + quad * 8);
        bf16x8 k1 = *(const bf16x8*)(qb + (size_t)(m0 + lr) * D_ + 32 + quad * 8);
        f32x4 s = {};
        s = MFMA16(a0, k0, s);
        s = MFMA16(a1, k1, s);
#pragma unroll
        for (int r = 0; r < 4; r++) {
            float sv = s[r];
            float mn = fmaxf(mr[r], sv);
            sr[r] = sr[r] * __expf(mr[r] - mn) + __expf(sv - mn);
            mr[r] = mn;
        }
    }
#pragma unroll
    for (int off = 1; off < 16; off <<= 1) {
#pragma unroll
        for (int r = 0; r < 4; r++) {
            float om = __shfl_xor(mr[r], off);
            float os = __shfl_xor(sr[r], off);
            float mn = fmaxf(mr[r], om);
            sr[r] = sr[r] * __expf(mr[r] - mn) + os * __expf(om - mn);
            mr[r] = mn;
        }
    }
    float rm[4], ri[4];
#pragma unroll
    for (int r = 0; r < 4; r++) { rm[r] = mr[r]; ri[r] = 1.0f / sr[r]; }

    // ---- pass 2: recompute S, write P via LDS staging ----
    for (int m0b = 0; m0b < N_; m0b += 128) {
#pragma unroll
        for (int sub = 0; sub < 8; sub++) {
            int mm = m0b + sub * 16;
            bf16x8 k0 = *(const bf16x8*)(qb + (size_t)(mm + lr) * D_ + quad * 8);
            bf16x8 k1 = *(const bf16x8*)(qb + (size_t)(mm + lr) * D_ + 32 + quad * 8);
            f32x4 s = {};
            s = MFMA16(a0, k0, s);
            s = MFMA16(a1, k1, s);
#pragma unroll
            for (int r = 0; r < 4; r++) {
                float p = __expf(s[r] - rm[r]) * ri[r];
                pbuf[wave][quad * 4 + r][sub * 16 + lr] = __float2bfloat16(p);
            }
        }
        // flush: per-wave private buffer, same-wave RAW (lgkmcnt handles it)
        int row = lane >> 2;
#pragma unroll
        for (int it = 0; it < 4; it++) {
            int col = it * 32 + (lane & 3) * 8;
            bf16x8 frag = *(const bf16x8*)&pbuf[wave][row][col];
            *(bf16x8*)(Pb + (size_t)(q0 + row) * N_ + m0b + col) = frag;
        }
    }
}

// ---------------------------------------------------------------------------
// K4: O[n][c] = sum_m P[n][m] * v[c][m], + flat residual (reshape quirk).
// ---------------------------------------------------------------------------
__global__ __launch_bounds__(256) void k_pv_gemm(
        const __hip_bfloat16* __restrict__ P,
        const __hip_bfloat16* __restrict__ v,
        const float* __restrict__ x, float* __restrict__ out) {
    __shared__ __hip_bfloat16 As[128 * 32];
    __shared__ __hip_bfloat16 Bs[128 * 32];
    int b = blockIdx.z;
    int t = threadIdx.x;
    int wave = t >> 6, lane = t & 63, lr = lane & 15, quad = lane >> 4;
    int wm = wave >> 1, wn = wave & 1;
    int n_blk = blockIdx.y * 128;
    int c_blk = blockIdx.x * 128;
    const __hip_bfloat16* Pb = P + ((size_t)b << 20);
    const __hip_bfloat16* vb = v + (size_t)b * (C_ * N_);

    f32x4 acc[4][4] = {};
    for (int kk = 0; kk < N_; kk += 32) {
#pragma unroll
        for (int j = 0; j < 2; j++) {
            int row = j * 64 + (t >> 2);
            int col = kk + (t & 3) * 8;
            load_lds16(Pb + (size_t)(n_blk + row) * N_ + col, &As[j * 2048 + t * 8]);
            load_lds16(vb + (size_t)(c_blk + row) * N_ + col, &Bs[j * 2048 + t * 8]);
        }
        __syncthreads();
        bf16x8 af[4], bfr[4];
#pragma unroll
        for (int i = 0; i < 4; i++) {
            af[i] = *(const bf16x8*)&As[(wm * 64 + i * 16 + lr) * 32 + quad * 8];
            bfr[i] = *(const bf16x8*)&Bs[(wn * 64 + i * 16 + lr) * 32 + quad * 8];
        }
#pragma unroll
        for (int mt = 0; mt < 4; mt++)
#pragma unroll
            for (int nt = 0; nt < 4; nt++)
                acc[mt][nt] = MFMA16(af[mt], bfr[nt], acc[mt][nt]);
        __syncthreads();
    }

    const float* xb = x + (size_t)b * (N_ * C_);
    float* ob = out + (size_t)b * (N_ * C_);
#pragma unroll
    for (int mt = 0; mt < 4; mt++) {
#pragma unroll
        for (int nt = 0; nt < 4; nt++) {
#pragma unroll
            for (int r = 0; r < 4; r++) {
                int n = n_blk + wm * 64 + mt * 16 + quad * 4 + r;
                int c = c_blk + wn * 64 + nt * 16 + lr;
                size_t idx = (size_t)n * C_ + c;
                ob[idx] = xb[idx] + acc[mt][nt][r];
            }
        }
    }
}

// ---------------------------------------------------------------------------
extern "C" void kernel_launch(void* const* d_in, const int* in_sizes, int n_in,
                              void* d_out, int out_size, void* d_ws, size_t ws_size,
                              hipStream_t stream) {
    const float* x  = (const float*)d_in[0];
    const float* w1 = (const float*)d_in[1];
    const float* b1 = (const float*)d_in[2];
    const float* w2 = (const float*)d_in[3];
    const float* b2 = (const float*)d_in[4];
    float* out = (float*)d_out;

    char* ws = (char*)d_ws;
    size_t off = 0;
    __hip_bfloat16* Wbf = (__hip_bfloat16*)(ws + off); off += (size_t)OPAD * C_ * 2;
    __hip_bfloat16* xT  = (__hip_bfloat16*)(ws + off); off += (size_t)B_ * N_ * C_ * 2;
    __hip_bfloat16* qkT = (__hip_bfloat16*)(ws + off); off += (size_t)B_ * N_ * D_ * 2;
    __hip_bfloat16* v   = (__hip_bfloat16*)(ws + off); off += (size_t)B_ * C_ * N_ * 2;
    __hip_bfloat16* P   = (__hip_bfloat16*)(ws + off); off += (size_t)B_ * N_ * N_ * 2;

    hipLaunchKernelGGL(k_cast_weights, dim3((OPAD * C_ + 255) / 256), dim3(256), 0, stream,
                       w1, w2, Wbf);
    hipLaunchKernelGGL(k_transpose_cast, dim3(N_ / 32, C_ / 32, B_), dim3(32, 8), 0, stream,
                       x, xT);
    hipLaunchKernelGGL(k_gemm_qkv, dim3(N_ / 128, OPAD / 128, B_), dim3(256), 0, stream,
                       Wbf, xT, b1, b2, qkT, v);
    hipLaunchKernelGGL(k_softmax_p, dim3(N_ / 64, B_), dim3(256), 0, stream,
                       qkT, P);
    hipLaunchKernelGGL(k_pv_gemm, dim3(C_ / 128, N_ / 128, B_), dim3(256), 0, stream,
                       P, v, x, out);
}

// Round 4
// 255.641 us; speedup vs baseline: 3.2339x; 1.1384x over previous
//
#include <hip/hip_runtime.h>
#include <hip/hip_bf16.h>
#include <math.h>

#define B_ 32
#define C_ 512
#define N_ 1024
#define D_ 64
#define OPAD 640   // D + C = 576 output channels, padded to 640 for 128-row tiles

typedef __attribute__((ext_vector_type(4))) float f32x4;
typedef __attribute__((ext_vector_type(4))) float float4v;
typedef __attribute__((ext_vector_type(8))) __bf16 bf16x8;

#define MFMA16(a, b, c) __builtin_amdgcn_mfma_f32_16x16x32_bf16((a), (b), (c), 0, 0, 0)

__device__ inline void load_lds16(const void* g, void* l) {
    __builtin_amdgcn_global_load_lds(
        (const __attribute__((address_space(1))) void*)g,
        (__attribute__((address_space(3))) void*)l, 16, 0, 0);
}

// ---------------------------------------------------------------------------
// K1a: cast w1 (rows 0..63) + w2 (rows 64..575) into bf16 W [640,512]
// ---------------------------------------------------------------------------
__global__ void k_cast_weights(const float* __restrict__ w1,
                               const float* __restrict__ w2,
                               __hip_bfloat16* __restrict__ Wbf) {
    int idx = blockIdx.x * 256 + threadIdx.x;
    if (idx >= OPAD * C_) return;
    int m = idx >> 9;
    int k = idx & (C_ - 1);
    float val = (m < D_) ? w1[m * C_ + k]
              : (m < D_ + C_) ? w2[(m - D_) * C_ + k] : 0.0f;
    Wbf[idx] = __float2bfloat16(val);
}

// ---------------------------------------------------------------------------
// K1b: transpose-cast x [B,C,N] fp32 -> xT [B,N,C] bf16.
// 64x64 tiles: float4 global reads (256B segments), bf16x8 16B global writes.
// ---------------------------------------------------------------------------
__global__ __launch_bounds__(256) void k_transpose_cast(
        const float* __restrict__ x, __hip_bfloat16* __restrict__ xT) {
    __shared__ float tile[64][68];
    int b = blockIdx.z;
    int n0 = blockIdx.x * 64;
    int c0 = blockIdx.y * 64;
    int t = threadIdx.x;
    const float* xb = x + (size_t)b * (C_ * N_);
#pragma unroll
    for (int i = 0; i < 4; i++) {
        int c = i * 16 + (t >> 4);
        int nc = (t & 15) * 4;
        *(float4v*)&tile[c][nc] =
            *(const float4v*)(xb + (size_t)(c0 + c) * N_ + n0 + nc);
    }
    __syncthreads();
    __hip_bfloat16* xTb = xT + (size_t)b * (N_ * C_);
#pragma unroll
    for (int i = 0; i < 2; i++) {
        int n = i * 32 + (t >> 3);
        int cs = (t & 7) * 8;
        alignas(16) __hip_bfloat16 tmp[8];
#pragma unroll
        for (int j = 0; j < 8; j++)
            tmp[j] = __float2bfloat16(tile[cs + j][n]);
        *(bf16x8*)(xTb + (size_t)(n0 + n) * C_ + c0 + cs) = *(bf16x8*)tmp;
    }
}

// ---------------------------------------------------------------------------
// K2: LDS-staged GEMM  W[640,512] x xT -> qkT [B,N,D] + v [B,C,N].
// m97 structure. v-epilogue staged through LDS for 16B coalesced stores.
// ---------------------------------------------------------------------------
__global__ __launch_bounds__(256) void k_gemm_qkv(
        const __hip_bfloat16* __restrict__ Wbf,
        const __hip_bfloat16* __restrict__ xT,
        const float* __restrict__ b1, const float* __restrict__ b2,
        __hip_bfloat16* __restrict__ qkT, __hip_bfloat16* __restrict__ v) {
    __shared__ __hip_bfloat16 As[128 * 32];
    __shared__ __hip_bfloat16 Bs[128 * 32];
    __shared__ __hip_bfloat16 epi[4][16][72];
    int b = blockIdx.z;
    int t = threadIdx.x;
    int wave = t >> 6, lane = t & 63, lr = lane & 15, quad = lane >> 4;
    int wm = wave >> 1, wn = wave & 1;
    int m_blk = blockIdx.y * 128;
    int n_blk = blockIdx.x * 128;
    const __hip_bfloat16* xTb = xT + (size_t)b * (N_ * C_);

    f32x4 acc[4][4] = {};
    for (int kk = 0; kk < C_; kk += 32) {
#pragma unroll
        for (int j = 0; j < 2; j++) {
            int row = j * 64 + (t >> 2);
            int col = kk + (t & 3) * 8;
            load_lds16(Wbf + (size_t)(m_blk + row) * C_ + col, &As[j * 2048 + t * 8]);
            load_lds16(xTb + (size_t)(n_blk + row) * C_ + col, &Bs[j * 2048 + t * 8]);
        }
        __syncthreads();
        bf16x8 af[4], bfr[4];
#pragma unroll
        for (int i = 0; i < 4; i++) {
            af[i] = *(const bf16x8*)&As[(wm * 64 + i * 16 + lr) * 32 + quad * 8];
            bfr[i] = *(const bf16x8*)&Bs[(wn * 64 + i * 16 + lr) * 32 + quad * 8];
        }
#pragma unroll
        for (int mt = 0; mt < 4; mt++)
#pragma unroll
            for (int nt = 0; nt < 4; nt++)
                acc[mt][nt] = MFMA16(af[mt], bfr[nt], acc[mt][nt]);
        __syncthreads();
    }

#pragma unroll
    for (int mt = 0; mt < 4; mt++) {
        int m_frag = m_blk + wm * 64 + mt * 16;
        if (m_frag >= D_ + C_) continue;
        int m0 = m_frag + quad * 4;
        if (m_frag < D_) {
#pragma unroll
            for (int nt = 0; nt < 4; nt++) {
                int n = n_blk + wn * 64 + nt * 16 + lr;
                alignas(8) __hip_bfloat16 tmp[4];
#pragma unroll
                for (int r = 0; r < 4; r++)
                    tmp[r] = __float2bfloat16(acc[mt][nt][r] + b1[m0 + r]);
                *reinterpret_cast<short4*>(qkT + ((size_t)b * N_ + n) * D_ + m0) =
                    *reinterpret_cast<short4*>(tmp);
            }
        } else {
#pragma unroll
            for (int nt = 0; nt < 4; nt++) {
#pragma unroll
                for (int r = 0; r < 4; r++) {
                    int c = m0 - D_ + r;
                    epi[wave][quad * 4 + r][nt * 16 + lr] =
                        __float2bfloat16(acc[mt][nt][r] + b2[c]);
                }
            }
            int cbase = m_frag - D_;
            int row = lane >> 2;
#pragma unroll
            for (int it = 0; it < 2; it++) {
                int col = it * 32 + (lane & 3) * 8;
                bf16x8 frag = *(const bf16x8*)&epi[wave][row][col];
                *(bf16x8*)(v + (size_t)(b * C_ + cbase + row) * N_
                             + n_blk + wn * 64 + col) = frag;
            }
        }
    }
}

// ---------------------------------------------------------------------------
// K3: softmax producing UNNORMALIZED P~ = exp(S - rowmax) and rowinv = 1/sum.
// Pass 1: max only (LDS-staged K, no exp). Pass 2: exp + sum + 16B stores.
// 1/sum is folded into k_pv_gemm's epilogue.
// grid (N/64, B), 4 waves x 16 q-rows.
// ---------------------------------------------------------------------------
__global__ __launch_bounds__(256) void k_softmax_p(
        const __hip_bfloat16* __restrict__ qkT,
        float* __restrict__ rowinv, __hip_bfloat16* __restrict__ P) {
    __shared__ __hip_bfloat16 Ks[128][72];       // K-chunk, padded (b128 conflict-free)
    __shared__ __hip_bfloat16 pbuf[4][16][136];  // per-wave P staging
    int b = blockIdx.y;
    int t = threadIdx.x;
    int wave = t >> 6, lane = t & 63, lr = lane & 15, quad = lane >> 4;
    int q0 = blockIdx.x * 64 + wave * 16;
    const __hip_bfloat16* qb = qkT + (size_t)b * (N_ * D_);
    __hip_bfloat16* Pb = P + ((size_t)b << 20);

    bf16x8 a0 = *(const bf16x8*)(qb + (size_t)(q0 + lr) * D_ + quad * 8);
    bf16x8 a1 = *(const bf16x8*)(qb + (size_t)(q0 + lr) * D_ + 32 + quad * 8);

    float mr[4];
#pragma unroll
    for (int r = 0; r < 4; r++) mr[r] = -INFINITY;

    // ---- pass 1: row max ----
    for (int mc = 0; mc < N_; mc += 128) {
#pragma unroll
        for (int i = 0; i < 4; i++) {
            int row = i * 32 + (t >> 3);
            int col = (t & 7) * 8;
            *(bf16x8*)&Ks[row][col] =
                *(const bf16x8*)(qb + (size_t)(mc + row) * D_ + col);
        }
        __syncthreads();
#pragma unroll
        for (int sub = 0; sub < 8; sub++) {
            bf16x8 k0 = *(const bf16x8*)&Ks[sub * 16 + lr][quad * 8];
            bf16x8 k1 = *(const bf16x8*)&Ks[sub * 16 + lr][32 + quad * 8];
            f32x4 s = {};
            s = MFMA16(a0, k0, s);
            s = MFMA16(a1, k1, s);
#pragma unroll
            for (int r = 0; r < 4; r++) mr[r] = fmaxf(mr[r], s[r]);
        }
        __syncthreads();
    }
#pragma unroll
    for (int off = 1; off < 16; off <<= 1)
#pragma unroll
        for (int r = 0; r < 4; r++)
            mr[r] = fmaxf(mr[r], __shfl_xor(mr[r], off));

    // ---- pass 2: exp, sum, store unnormalized P~ ----
    float sr[4] = {0.f, 0.f, 0.f, 0.f};
    for (int mc = 0; mc < N_; mc += 128) {
#pragma unroll
        for (int i = 0; i < 4; i++) {
            int row = i * 32 + (t >> 3);
            int col = (t & 7) * 8;
            *(bf16x8*)&Ks[row][col] =
                *(const bf16x8*)(qb + (size_t)(mc + row) * D_ + col);
        }
        __syncthreads();
#pragma unroll
        for (int sub = 0; sub < 8; sub++) {
            bf16x8 k0 = *(const bf16x8*)&Ks[sub * 16 + lr][quad * 8];
            bf16x8 k1 = *(const bf16x8*)&Ks[sub * 16 + lr][32 + quad * 8];
            f32x4 s = {};
            s = MFMA16(a0, k0, s);
            s = MFMA16(a1, k1, s);
#pragma unroll
            for (int r = 0; r < 4; r++) {
                float e = __expf(s[r] - mr[r]);
                sr[r] += e;
                pbuf[wave][quad * 4 + r][sub * 16 + lr] = __float2bfloat16(e);
            }
        }
        // flush per-wave P tile: 16B coalesced stores (same-wave RAW via lgkmcnt)
        int row = lane >> 2;
#pragma unroll
        for (int it = 0; it < 4; it++) {
            int col = it * 32 + (lane & 3) * 8;
            bf16x8 frag = *(const bf16x8*)&pbuf[wave][row][col];
            *(bf16x8*)(Pb + (size_t)(q0 + row) * N_ + mc + col) = frag;
        }
        __syncthreads();
    }
#pragma unroll
    for (int off = 1; off < 16; off <<= 1)
#pragma unroll
        for (int r = 0; r < 4; r++)
            sr[r] += __shfl_xor(sr[r], off);
    if (lr == 0) {
#pragma unroll
        for (int r = 0; r < 4; r++)
            rowinv[b * N_ + q0 + quad * 4 + r] = 1.0f / sr[r];
    }
}

// ---------------------------------------------------------------------------
// K4: O[n][c] = rowinv[n] * sum_m P~[n][m] * v[c][m], + flat residual.
// ---------------------------------------------------------------------------
__global__ __launch_bounds__(256) void k_pv_gemm(
        const __hip_bfloat16* __restrict__ P,
        const __hip_bfloat16* __restrict__ v,
        const float* __restrict__ rowinv,
        const float* __restrict__ x, float* __restrict__ out) {
    __shared__ __hip_bfloat16 As[128 * 32];
    __shared__ __hip_bfloat16 Bs[128 * 32];
    int b = blockIdx.z;
    int t = threadIdx.x;
    int wave = t >> 6, lane = t & 63, lr = lane & 15, quad = lane >> 4;
    int wm = wave >> 1, wn = wave & 1;
    int n_blk = blockIdx.y * 128;
    int c_blk = blockIdx.x * 128;
    const __hip_bfloat16* Pb = P + ((size_t)b << 20);
    const __hip_bfloat16* vb = v + (size_t)b * (C_ * N_);

    f32x4 acc[4][4] = {};
    for (int kk = 0; kk < N_; kk += 32) {
#pragma unroll
        for (int j = 0; j < 2; j++) {
            int row = j * 64 + (t >> 2);
            int col = kk + (t & 3) * 8;
            load_lds16(Pb + (size_t)(n_blk + row) * N_ + col, &As[j * 2048 + t * 8]);
            load_lds16(vb + (size_t)(c_blk + row) * N_ + col, &Bs[j * 2048 + t * 8]);
        }
        __syncthreads();
        bf16x8 af[4], bfr[4];
#pragma unroll
        for (int i = 0; i < 4; i++) {
            af[i] = *(const bf16x8*)&As[(wm * 64 + i * 16 + lr) * 32 + quad * 8];
            bfr[i] = *(const bf16x8*)&Bs[(wn * 64 + i * 16 + lr) * 32 + quad * 8];
        }
#pragma unroll
        for (int mt = 0; mt < 4; mt++)
#pragma unroll
            for (int nt = 0; nt < 4; nt++)
                acc[mt][nt] = MFMA16(af[mt], bfr[nt], acc[mt][nt]);
        __syncthreads();
    }

    const float* xb = x + (size_t)b * (N_ * C_);
    float* ob = out + (size_t)b * (N_ * C_);
#pragma unroll
    for (int mt = 0; mt < 4; mt++) {
        float ri[4];
#pragma unroll
        for (int r = 0; r < 4; r++)
            ri[r] = rowinv[b * N_ + n_blk + wm * 64 + mt * 16 + quad * 4 + r];
#pragma unroll
        for (int nt = 0; nt < 4; nt++) {
#pragma unroll
            for (int r = 0; r < 4; r++) {
                int n = n_blk + wm * 64 + mt * 16 + quad * 4 + r;
                int c = c_blk + wn * 64 + nt * 16 + lr;
                size_t idx = (size_t)n * C_ + c;
                ob[idx] = xb[idx] + ri[r] * acc[mt][nt][r];
            }
        }
    }
}

// ---------------------------------------------------------------------------
extern "C" void kernel_launch(void* const* d_in, const int* in_sizes, int n_in,
                              void* d_out, int out_size, void* d_ws, size_t ws_size,
                              hipStream_t stream) {
    const float* x  = (const float*)d_in[0];
    const float* w1 = (const float*)d_in[1];
    const float* b1 = (const float*)d_in[2];
    const float* w2 = (const float*)d_in[3];
    const float* b2 = (const float*)d_in[4];
    float* out = (float*)d_out;

    char* ws = (char*)d_ws;
    size_t off = 0;
    __hip_bfloat16* Wbf = (__hip_bfloat16*)(ws + off); off += (size_t)OPAD * C_ * 2;
    __hip_bfloat16* xT  = (__hip_bfloat16*)(ws + off); off += (size_t)B_ * N_ * C_ * 2;
    __hip_bfloat16* qkT = (__hip_bfloat16*)(ws + off); off += (size_t)B_ * N_ * D_ * 2;
    __hip_bfloat16* v   = (__hip_bfloat16*)(ws + off); off += (size_t)B_ * C_ * N_ * 2;
    float* rowinv = (float*)(ws + off); off += (size_t)B_ * N_ * 4;
    __hip_bfloat16* P = (__hip_bfloat16*)(ws + off); off += (size_t)B_ * N_ * N_ * 2;

    hipLaunchKernelGGL(k_cast_weights, dim3((OPAD * C_ + 255) / 256), dim3(256), 0, stream,
                       w1, w2, Wbf);
    hipLaunchKernelGGL(k_transpose_cast, dim3(N_ / 64, C_ / 64, B_), dim3(256), 0, stream,
                       x, xT);
    hipLaunchKernelGGL(k_gemm_qkv, dim3(N_ / 128, OPAD / 128, B_), dim3(256), 0, stream,
                       Wbf, xT, b1, b2, qkT, v);
    hipLaunchKernelGGL(k_softmax_p, dim3(N_ / 64, B_), dim3(256), 0, stream,
                       qkT, rowinv, P);
    hipLaunchKernelGGL(k_pv_gemm, dim3(C_ / 128, N_ / 128, B_), dim3(256), 0, stream,
                       P, v, rowinv, x, out);
}

// Round 5
// 243.545 us; speedup vs baseline: 3.3945x; 1.0497x over previous
//
#include <hip/hip_runtime.h>
#include <hip/hip_bf16.h>
#include <math.h>

#define B_ 32
#define C_ 512
#define N_ 1024
#define D_ 64
#define OPAD 640   // D + C = 576 output channels, padded to 640 for 128-row tiles

typedef __attribute__((ext_vector_type(4))) float f32x4;
typedef __attribute__((ext_vector_type(4))) float float4v;
typedef __attribute__((ext_vector_type(8))) __bf16 bf16x8;

#define MFMA16(a, b, c) __builtin_amdgcn_mfma_f32_16x16x32_bf16((a), (b), (c), 0, 0, 0)

__device__ inline void load_lds16(const void* g, void* l) {
    __builtin_amdgcn_global_load_lds(
        (const __attribute__((address_space(1))) void*)g,
        (__attribute__((address_space(3))) void*)l, 16, 0, 0);
}

// ---------------------------------------------------------------------------
// K1a: cast w1 (rows 0..63) + w2 (rows 64..575) into bf16 W [640,512]
// ---------------------------------------------------------------------------
__global__ void k_cast_weights(const float* __restrict__ w1,
                               const float* __restrict__ w2,
                               __hip_bfloat16* __restrict__ Wbf) {
    int idx = blockIdx.x * 256 + threadIdx.x;
    if (idx >= OPAD * C_) return;
    int m = idx >> 9;
    int k = idx & (C_ - 1);
    float val = (m < D_) ? w1[m * C_ + k]
              : (m < D_ + C_) ? w2[(m - D_) * C_ + k] : 0.0f;
    Wbf[idx] = __float2bfloat16(val);
}

// ---------------------------------------------------------------------------
// K1b: transpose-cast x [B,C,N] fp32 -> xT [B,N,C] bf16.
// ---------------------------------------------------------------------------
__global__ __launch_bounds__(256) void k_transpose_cast(
        const float* __restrict__ x, __hip_bfloat16* __restrict__ xT) {
    __shared__ float tile[64][68];
    int b = blockIdx.z;
    int n0 = blockIdx.x * 64;
    int c0 = blockIdx.y * 64;
    int t = threadIdx.x;
    const float* xb = x + (size_t)b * (C_ * N_);
#pragma unroll
    for (int i = 0; i < 4; i++) {
        int c = i * 16 + (t >> 4);
        int nc = (t & 15) * 4;
        *(float4v*)&tile[c][nc] =
            *(const float4v*)(xb + (size_t)(c0 + c) * N_ + n0 + nc);
    }
    __syncthreads();
    __hip_bfloat16* xTb = xT + (size_t)b * (N_ * C_);
#pragma unroll
    for (int i = 0; i < 2; i++) {
        int n = i * 32 + (t >> 3);
        int cs = (t & 7) * 8;
        alignas(16) __hip_bfloat16 tmp[8];
#pragma unroll
        for (int j = 0; j < 8; j++)
            tmp[j] = __float2bfloat16(tile[cs + j][n]);
        *(bf16x8*)(xTb + (size_t)(n0 + n) * C_ + c0 + cs) = *(bf16x8*)tmp;
    }
}

// ---------------------------------------------------------------------------
// K2: LDS-staged GEMM  W[640,512] x xT -> qkT [B,N,D] + v [B,C,N].
// BK=64, XOR-swizzled LDS (chunk c of row r at c^(r&7)) -> conflict-free
// b128 frag reads, global coalescing preserved (permutation within a row).
// ---------------------------------------------------------------------------
__global__ __launch_bounds__(256) void k_gemm_qkv(
        const __hip_bfloat16* __restrict__ Wbf,
        const __hip_bfloat16* __restrict__ xT,
        const float* __restrict__ b1, const float* __restrict__ b2,
        __hip_bfloat16* __restrict__ qkT, __hip_bfloat16* __restrict__ v) {
    __shared__ __hip_bfloat16 As[128 * 64];   // 16 KB
    __shared__ __hip_bfloat16 Bs[128 * 64];   // 16 KB
    __shared__ __hip_bfloat16 epi[4][16][72];
    int b = blockIdx.z;
    int t = threadIdx.x;
    int wave = t >> 6, lane = t & 63, lr = lane & 15, quad = lane >> 4;
    int wm = wave >> 1, wn = wave & 1;
    int m_blk = blockIdx.y * 128;
    int n_blk = blockIdx.x * 128;
    const __hip_bfloat16* xTb = xT + (size_t)b * (N_ * C_);

    f32x4 acc[4][4] = {};
    for (int kk = 0; kk < C_; kk += 64) {
#pragma unroll
        for (int i = 0; i < 4; i++) {
            int id = i * 256 + t;
            int r = id >> 3, cx = id & 7;
            int gc = cx ^ (r & 7);
            load_lds16(Wbf + (size_t)(m_blk + r) * C_ + kk + gc * 8, &As[id * 8]);
            load_lds16(xTb + (size_t)(n_blk + r) * C_ + kk + gc * 8, &Bs[id * 8]);
        }
        __syncthreads();
#pragma unroll
        for (int h = 0; h < 2; h++) {
            bf16x8 af[4], bfr[4];
#pragma unroll
            for (int i = 0; i < 4; i++) {
                int ra = wm * 64 + i * 16 + lr;
                int rb = wn * 64 + i * 16 + lr;
                int q = h * 4 + quad;
                af[i]  = *(const bf16x8*)&As[ra * 64 + (q ^ (lr & 7)) * 8];
                bfr[i] = *(const bf16x8*)&Bs[rb * 64 + (q ^ (lr & 7)) * 8];
            }
#pragma unroll
            for (int mt = 0; mt < 4; mt++)
#pragma unroll
                for (int nt = 0; nt < 4; nt++)
                    acc[mt][nt] = MFMA16(af[mt], bfr[nt], acc[mt][nt]);
        }
        __syncthreads();
    }

#pragma unroll
    for (int mt = 0; mt < 4; mt++) {
        int m_frag = m_blk + wm * 64 + mt * 16;
        if (m_frag >= D_ + C_) continue;
        int m0 = m_frag + quad * 4;
        if (m_frag < D_) {
#pragma unroll
            for (int nt = 0; nt < 4; nt++) {
                int n = n_blk + wn * 64 + nt * 16 + lr;
                alignas(8) __hip_bfloat16 tmp[4];
#pragma unroll
                for (int r = 0; r < 4; r++)
                    tmp[r] = __float2bfloat16(acc[mt][nt][r] + b1[m0 + r]);
                *reinterpret_cast<short4*>(qkT + ((size_t)b * N_ + n) * D_ + m0) =
                    *reinterpret_cast<short4*>(tmp);
            }
        } else {
#pragma unroll
            for (int nt = 0; nt < 4; nt++) {
#pragma unroll
                for (int r = 0; r < 4; r++) {
                    int c = m0 - D_ + r;
                    epi[wave][quad * 4 + r][nt * 16 + lr] =
                        __float2bfloat16(acc[mt][nt][r] + b2[c]);
                }
            }
            int cbase = m_frag - D_;
            int row = lane >> 2;
#pragma unroll
            for (int it = 0; it < 2; it++) {
                int col = it * 32 + (lane & 3) * 8;
                bf16x8 frag = *(const bf16x8*)&epi[wave][row][col];
                *(bf16x8*)(v + (size_t)(b * C_ + cbase + row) * N_
                             + n_blk + wn * 64 + col) = frag;
            }
        }
    }
}

// ---------------------------------------------------------------------------
// K3: softmax producing UNNORMALIZED P~ = exp(S - rowmax) and rowinv = 1/sum.
// ---------------------------------------------------------------------------
__global__ __launch_bounds__(256) void k_softmax_p(
        const __hip_bfloat16* __restrict__ qkT,
        float* __restrict__ rowinv, __hip_bfloat16* __restrict__ P) {
    __shared__ __hip_bfloat16 Ks[128][72];
    __shared__ __hip_bfloat16 pbuf[4][16][136];
    int b = blockIdx.y;
    int t = threadIdx.x;
    int wave = t >> 6, lane = t & 63, lr = lane & 15, quad = lane >> 4;
    int q0 = blockIdx.x * 64 + wave * 16;
    const __hip_bfloat16* qb = qkT + (size_t)b * (N_ * D_);
    __hip_bfloat16* Pb = P + ((size_t)b << 20);

    bf16x8 a0 = *(const bf16x8*)(qb + (size_t)(q0 + lr) * D_ + quad * 8);
    bf16x8 a1 = *(const bf16x8*)(qb + (size_t)(q0 + lr) * D_ + 32 + quad * 8);

    float mr[4];
#pragma unroll
    for (int r = 0; r < 4; r++) mr[r] = -INFINITY;

    for (int mc = 0; mc < N_; mc += 128) {
#pragma unroll
        for (int i = 0; i < 4; i++) {
            int row = i * 32 + (t >> 3);
            int col = (t & 7) * 8;
            *(bf16x8*)&Ks[row][col] =
                *(const bf16x8*)(qb + (size_t)(mc + row) * D_ + col);
        }
        __syncthreads();
#pragma unroll
        for (int sub = 0; sub < 8; sub++) {
            bf16x8 k0 = *(const bf16x8*)&Ks[sub * 16 + lr][quad * 8];
            bf16x8 k1 = *(const bf16x8*)&Ks[sub * 16 + lr][32 + quad * 8];
            f32x4 s = {};
            s = MFMA16(a0, k0, s);
            s = MFMA16(a1, k1, s);
#pragma unroll
            for (int r = 0; r < 4; r++) mr[r] = fmaxf(mr[r], s[r]);
        }
        __syncthreads();
    }
#pragma unroll
    for (int off = 1; off < 16; off <<= 1)
#pragma unroll
        for (int r = 0; r < 4; r++)
            mr[r] = fmaxf(mr[r], __shfl_xor(mr[r], off));

    float sr[4] = {0.f, 0.f, 0.f, 0.f};
    for (int mc = 0; mc < N_; mc += 128) {
#pragma unroll
        for (int i = 0; i < 4; i++) {
            int row = i * 32 + (t >> 3);
            int col = (t & 7) * 8;
            *(bf16x8*)&Ks[row][col] =
                *(const bf16x8*)(qb + (size_t)(mc + row) * D_ + col);
        }
        __syncthreads();
#pragma unroll
        for (int sub = 0; sub < 8; sub++) {
            bf16x8 k0 = *(const bf16x8*)&Ks[sub * 16 + lr][quad * 8];
            bf16x8 k1 = *(const bf16x8*)&Ks[sub * 16 + lr][32 + quad * 8];
            f32x4 s = {};
            s = MFMA16(a0, k0, s);
            s = MFMA16(a1, k1, s);
#pragma unroll
            for (int r = 0; r < 4; r++) {
                float e = __expf(s[r] - mr[r]);
                sr[r] += e;
                pbuf[wave][quad * 4 + r][sub * 16 + lr] = __float2bfloat16(e);
            }
        }
        int row = lane >> 2;
#pragma unroll
        for (int it = 0; it < 4; it++) {
            int col = it * 32 + (lane & 3) * 8;
            bf16x8 frag = *(const bf16x8*)&pbuf[wave][row][col];
            *(bf16x8*)(Pb + (size_t)(q0 + row) * N_ + mc + col) = frag;
        }
        __syncthreads();
    }
#pragma unroll
    for (int off = 1; off < 16; off <<= 1)
#pragma unroll
        for (int r = 0; r < 4; r++)
            sr[r] += __shfl_xor(sr[r], off);
    if (lr == 0) {
#pragma unroll
        for (int r = 0; r < 4; r++)
            rowinv[b * N_ + q0 + quad * 4 + r] = 1.0f / sr[r];
    }
}

// ---------------------------------------------------------------------------
// K4: O[n][c] = rowinv[n] * sum_m P~[n][m] * v[c][m], + flat residual.
// BK=64, XOR-swizzled LDS, LDS-staged float4 epilogue (2 phases x 64 rows).
// ---------------------------------------------------------------------------
__global__ __launch_bounds__(256) void k_pv_gemm(
        const __hip_bfloat16* __restrict__ P,
        const __hip_bfloat16* __restrict__ v,
        const float* __restrict__ rowinv,
        const float* __restrict__ x, float* __restrict__ out) {
    __shared__ char smem[128 * 64 * 2 * 2];                  // 32 KB
    __hip_bfloat16* As = (__hip_bfloat16*)smem;              // [128][64]
    __hip_bfloat16* Bs = As + 128 * 64;
    float* Obuf = (float*)smem;                              // [64][128] fp32
    int b = blockIdx.z;
    int t = threadIdx.x;
    int wave = t >> 6, lane = t & 63, lr = lane & 15, quad = lane >> 4;
    int wm = wave >> 1, wn = wave & 1;
    int n_blk = blockIdx.y * 128;
    int c_blk = blockIdx.x * 128;
    const __hip_bfloat16* Pb = P + ((size_t)b << 20);
    const __hip_bfloat16* vb = v + (size_t)b * (C_ * N_);

    f32x4 acc[4][4] = {};
    for (int kk = 0; kk < N_; kk += 64) {
#pragma unroll
        for (int i = 0; i < 4; i++) {
            int id = i * 256 + t;
            int r = id >> 3, cx = id & 7;
            int gc = cx ^ (r & 7);
            load_lds16(Pb + (size_t)(n_blk + r) * N_ + kk + gc * 8, &As[id * 8]);
            load_lds16(vb + (size_t)(c_blk + r) * N_ + kk + gc * 8, &Bs[id * 8]);
        }
        __syncthreads();
#pragma unroll
        for (int h = 0; h < 2; h++) {
            bf16x8 af[4], bfr[4];
#pragma unroll
            for (int i = 0; i < 4; i++) {
                int ra = wm * 64 + i * 16 + lr;
                int rb = wn * 64 + i * 16 + lr;
                int q = h * 4 + quad;
                af[i]  = *(const bf16x8*)&As[ra * 64 + (q ^ (lr & 7)) * 8];
                bfr[i] = *(const bf16x8*)&Bs[rb * 64 + (q ^ (lr & 7)) * 8];
            }
#pragma unroll
            for (int mt = 0; mt < 4; mt++)
#pragma unroll
                for (int nt = 0; nt < 4; nt++)
                    acc[mt][nt] = MFMA16(af[mt], bfr[nt], acc[mt][nt]);
        }
        __syncthreads();
    }

    // epilogue: two 64-row phases through LDS; float4 coalesced x/out
    const float* xb = x + (size_t)b * (N_ * C_);
    float* ob = out + (size_t)b * (N_ * C_);
#pragma unroll
    for (int h = 0; h < 2; h++) {
        if (wm == h) {
#pragma unroll
            for (int mt = 0; mt < 4; mt++)
#pragma unroll
                for (int nt = 0; nt < 4; nt++)
#pragma unroll
                    for (int r = 0; r < 4; r++)
                        Obuf[(mt * 16 + quad * 4 + r) * 128 + wn * 64 + nt * 16 + lr] =
                            acc[mt][nt][r];
        }
        __syncthreads();
#pragma unroll
        for (int i = 0; i < 8; i++) {
            int id = i * 256 + t;
            int rl = id >> 5;             // 0..63
            int c4 = (id & 31) * 4;       // float4 col
            int n = n_blk + h * 64 + rl;
            float ri = rowinv[b * N_ + n];
            float4v o = *(const float4v*)&Obuf[rl * 128 + c4];
            size_t gidx = (size_t)n * C_ + c_blk + c4;
            float4v xv = *(const float4v*)(xb + gidx);
            float4v res;
            res.x = xv.x + ri * o.x;
            res.y = xv.y + ri * o.y;
            res.z = xv.z + ri * o.z;
            res.w = xv.w + ri * o.w;
            *(float4v*)(ob + gidx) = res;
        }
        __syncthreads();
    }
}

// ---------------------------------------------------------------------------
extern "C" void kernel_launch(void* const* d_in, const int* in_sizes, int n_in,
                              void* d_out, int out_size, void* d_ws, size_t ws_size,
                              hipStream_t stream) {
    const float* x  = (const float*)d_in[0];
    const float* w1 = (const float*)d_in[1];
    const float* b1 = (const float*)d_in[2];
    const float* w2 = (const float*)d_in[3];
    const float* b2 = (const float*)d_in[4];
    float* out = (float*)d_out;

    char* ws = (char*)d_ws;
    size_t off = 0;
    __hip_bfloat16* Wbf = (__hip_bfloat16*)(ws + off); off += (size_t)OPAD * C_ * 2;
    __hip_bfloat16* xT  = (__hip_bfloat16*)(ws + off); off += (size_t)B_ * N_ * C_ * 2;
    __hip_bfloat16* qkT = (__hip_bfloat16*)(ws + off); off += (size_t)B_ * N_ * D_ * 2;
    __hip_bfloat16* v   = (__hip_bfloat16*)(ws + off); off += (size_t)B_ * C_ * N_ * 2;
    float* rowinv = (float*)(ws + off); off += (size_t)B_ * N_ * 4;
    __hip_bfloat16* P = (__hip_bfloat16*)(ws + off); off += (size_t)B_ * N_ * N_ * 2;

    hipLaunchKernelGGL(k_cast_weights, dim3((OPAD * C_ + 255) / 256), dim3(256), 0, stream,
                       w1, w2, Wbf);
    hipLaunchKernelGGL(k_transpose_cast, dim3(N_ / 64, C_ / 64, B_), dim3(256), 0, stream,
                       x, xT);
    hipLaunchKernelGGL(k_gemm_qkv, dim3(N_ / 128, OPAD / 128, B_), dim3(256), 0, stream,
                       Wbf, xT, b1, b2, qkT, v);
    hipLaunchKernelGGL(k_softmax_p, dim3(N_ / 64, B_), dim3(256), 0, stream,
                       qkT, rowinv, P);
    hipLaunchKernelGGL(k_pv_gemm, dim3(C_ / 128, N_ / 128, B_), dim3(256), 0, stream,
                       P, v, rowinv, x, out);
}